// Round 2
// baseline (1147.901 us; speedup 1.0000x reference)
//
#include <hip/hip_runtime.h>
#include <hip/hip_bf16.h>
#include <stdint.h>

// ---------------- problem constants ----------------
#define M_DIM 8192            // B*S = 4*2048
#define N_DIM 11008
#define K_DIM 4096
#define BM 128
#define BN 128
#define BK 64
#define NT (K_DIM/BK)         // 64 K-steps
#define GRID_M (M_DIM/BM)     // 64
#define GRID_N (N_DIM/BN)     // 86
#define NWG (GRID_M*GRID_N)   // 5504 (divisible by 8 -> simple XCD swizzle ok)

typedef unsigned short ushort_t;
typedef __attribute__((ext_vector_type(8))) short  short8;
typedef __attribute__((ext_vector_type(8))) __bf16 bf16x8;
typedef __attribute__((ext_vector_type(4))) float  f32x4;

// float -> bf16, round-to-nearest-even
__device__ __forceinline__ ushort_t f2bf(float f){
  uint32_t u = __builtin_bit_cast(uint32_t, f);
  u += 0x7FFFu + ((u >> 16) & 1u);
  return (ushort_t)(u >> 16);
}

// async global->LDS, 16 bytes per lane; LDS dest is wave-uniform base + lane*16
__device__ __forceinline__ void gll16(const void* g, void* l){
  __builtin_amdgcn_global_load_lds(
      (const __attribute__((address_space(1))) void*)g,
      (__attribute__((address_space(3))) void*)l,
      16, 0, 0);
}

// ---------------- pre-pass converts (path A) ----------------
__global__ void cvt_x_kernel(const float* __restrict__ x, ushort_t* __restrict__ xb){
  const int TOT = 33554432/8;           // M*K/8 chunks
  for (int c = blockIdx.x*blockDim.x + threadIdx.x; c < TOT; c += gridDim.x*blockDim.x){
    size_t i = (size_t)c*8;
    float4 v0 = *(const float4*)(x+i);
    float4 v1 = *(const float4*)(x+i+4);
    short8 o;
    o[0]=(short)f2bf(v0.x); o[1]=(short)f2bf(v0.y); o[2]=(short)f2bf(v0.z); o[3]=(short)f2bf(v0.w);
    o[4]=(short)f2bf(v1.x); o[5]=(short)f2bf(v1.y); o[6]=(short)f2bf(v1.z); o[7]=(short)f2bf(v1.w);
    *(short8*)(xb+i) = o;
  }
}

__global__ void cvt_w_kernel(const int* __restrict__ q, const float* __restrict__ scale,
                             const float* __restrict__ zp, ushort_t* __restrict__ wb){
  const int TOT = 45088768/8;           // N*K/8 chunks
  for (int c = blockIdx.x*blockDim.x + threadIdx.x; c < TOT; c += gridDim.x*blockDim.x){
    int row = c >> 9;                   // K/8 = 512 chunks per row
    float s = scale[row];
    float b = -zp[row]*s;               // w = q*s + b
    size_t i = (size_t)c*8;
    int4 q0 = *(const int4*)(q+i);
    int4 q1 = *(const int4*)(q+i+4);
    short8 o;
    o[0]=(short)f2bf((float)q0.x*s+b); o[1]=(short)f2bf((float)q0.y*s+b);
    o[2]=(short)f2bf((float)q0.z*s+b); o[3]=(short)f2bf((float)q0.w*s+b);
    o[4]=(short)f2bf((float)q1.x*s+b); o[5]=(short)f2bf((float)q1.y*s+b);
    o[6]=(short)f2bf((float)q1.z*s+b); o[7]=(short)f2bf((float)q1.w*s+b);
    *(short8*)(wb+i) = o;
  }
}

// ---------------- GEMM: C[M][N] = A[M][K] * B[N][K]^T + bias ----------------
// 2-phase double-buffered K-loop (T3 minimum recipe):
//   prologue: STAGE(buf0, t=0)
//   loop t:   [explicit s_waitcnt vmcnt(0) lgkmcnt(0)] + barrier  -> buf[cur] ready
//             STAGE(buf[cur^1], t+1)   (DMA flies under compute)
//             compute buf[cur]
// Race-free by construction: each wave drains ITS OWN staging ops before the
// barrier; any reader touches a buffer only after the barrier that follows
// the drain of that buffer's writes.
template<bool PRE_A, bool PRE_B>
__global__ __launch_bounds__(256, 2)
void qgemm(const ushort_t* __restrict__ Xb, const float* __restrict__ Xf,
           const ushort_t* __restrict__ Wb, const int* __restrict__ Wq,
           const float* __restrict__ g_scale, const float* __restrict__ g_zp,
           const float* __restrict__ g_bias, float* __restrict__ Y)
{
  __shared__ __align__(16) ushort_t As[2][BM*BK];   // 2 x 16 KB
  __shared__ __align__(16) ushort_t Bs[2][BM*BK];   // 2 x 16 KB

  const int t    = threadIdx.x;
  const int lane = t & 63;
  const int w    = t >> 6;
  const int wr   = w >> 1, wc = w & 1;           // 2x2 wave grid, 64x64 each

  // XCD-aware bijective swizzle (NWG % 8 == 0)
  int bid = blockIdx.x;
  int swz = (bid & 7) * (NWG/8) + (bid >> 3);
  int by  = swz / GRID_N;
  int bx  = swz - by*GRID_N;
  const int brow = by*BM, bcol = bx*BN;

  f32x4 acc[4][4];
  #pragma unroll
  for (int i=0;i<4;++i)
    #pragma unroll
    for (int j=0;j<4;++j) acc[i][j] = (f32x4){0.f,0.f,0.f,0.f};

  // conv-path staging geometry: thread owns slot s8 of rows r0+32i
  const int s8 = t & 7;
  const int r0 = t >> 3;
  // gll-path geometry: chunk c covers 8 rows; lane -> (row-in-chunk, swizzled slot)
  const int g_r = lane >> 3;
  const int g_s = (lane & 7) ^ g_r;

  float wsc[4], wof[4];
  if constexpr (!PRE_B){
    #pragma unroll
    for (int i=0;i<4;++i){
      int n = bcol + r0 + 32*i;
      float sc = g_scale[n];
      wsc[i] = sc;
      wof[i] = -g_zp[n]*sc;
    }
  }

  float4 ax[4][2];
  int4   bq[4][2];

  auto loadA = [&](int kt){
    #pragma unroll
    for (int i=0;i<4;++i){
      const float* p = Xf + (size_t)(brow + r0 + 32*i)*K_DIM + kt*BK + s8*8;
      ax[i][0] = *(const float4*)p;
      ax[i][1] = *(const float4*)(p+4);
    }
  };
  auto loadB = [&](int kt){
    #pragma unroll
    for (int i=0;i<4;++i){
      const int* p = Wq + (size_t)(bcol + r0 + 32*i)*K_DIM + kt*BK + s8*8;
      bq[i][0] = *(const int4*)p;
      bq[i][1] = *(const int4*)(p+4);
    }
  };

  auto stageA_gll = [&](int buf, int kt){
    #pragma unroll
    for (int i=0;i<4;++i){
      int c = w*4 + i;
      gll16(Xb + (size_t)(brow + 8*c + g_r)*K_DIM + kt*BK + g_s*8, &As[buf][c*512]);
    }
  };
  auto stageB_gll = [&](int buf, int kt){
    #pragma unroll
    for (int i=0;i<4;++i){
      int c = w*4 + i;
      gll16(Wb + (size_t)(bcol + 8*c + g_r)*K_DIM + kt*BK + g_s*8, &Bs[buf][c*512]);
    }
  };

  // convert current regs and ds_write (XOR-swizzled) into buf
  auto stageA_reg = [&](int buf){
    #pragma unroll
    for (int i=0;i<4;++i){
      short8 o;
      o[0]=(short)f2bf(ax[i][0].x); o[1]=(short)f2bf(ax[i][0].y);
      o[2]=(short)f2bf(ax[i][0].z); o[3]=(short)f2bf(ax[i][0].w);
      o[4]=(short)f2bf(ax[i][1].x); o[5]=(short)f2bf(ax[i][1].y);
      o[6]=(short)f2bf(ax[i][1].z); o[7]=(short)f2bf(ax[i][1].w);
      int r = r0 + 32*i;
      int idx = (r*BK + s8*8) ^ ((r&7)<<3);
      *(short8*)&As[buf][idx] = o;
    }
  };
  auto stageB_reg = [&](int buf){
    #pragma unroll
    for (int i=0;i<4;++i){
      short8 o;
      o[0]=(short)f2bf((float)bq[i][0].x*wsc[i]+wof[i]);
      o[1]=(short)f2bf((float)bq[i][0].y*wsc[i]+wof[i]);
      o[2]=(short)f2bf((float)bq[i][0].z*wsc[i]+wof[i]);
      o[3]=(short)f2bf((float)bq[i][0].w*wsc[i]+wof[i]);
      o[4]=(short)f2bf((float)bq[i][1].x*wsc[i]+wof[i]);
      o[5]=(short)f2bf((float)bq[i][1].y*wsc[i]+wof[i]);
      o[6]=(short)f2bf((float)bq[i][1].z*wsc[i]+wof[i]);
      o[7]=(short)f2bf((float)bq[i][1].w*wsc[i]+wof[i]);
      int r = r0 + 32*i;
      int idx = (r*BK + s8*8) ^ ((r&7)<<3);
      *(short8*)&Bs[buf][idx] = o;
    }
  };

  // ---- prologue: tile 0 into buf 0; regs prefetch tile 1 (conv paths) ----
  if constexpr (!PRE_A) loadA(0);
  if constexpr (!PRE_B) loadB(0);
  if constexpr (PRE_A) stageA_gll(0, 0); else stageA_reg(0);
  if constexpr (PRE_B) stageB_gll(0, 0); else stageB_reg(0);
  if constexpr (!PRE_A) { if (NT > 1) loadA(1); }
  if constexpr (!PRE_B) { if (NT > 1) loadB(1); }

  int cur = 0;
  for (int kt=0; kt<NT; ++kt){
    // drain THIS wave's staging ops (DMA + ds_write + reg prefetch), then sync:
    // after this barrier, buf[cur] is complete and buf[cur^1] is free.
    asm volatile("s_waitcnt vmcnt(0) lgkmcnt(0)" ::: "memory");
    __builtin_amdgcn_sched_barrier(0);
    __syncthreads();

    const int nxt = cur ^ 1;
    if (kt+1 < NT){
      if constexpr (PRE_A) stageA_gll(nxt, kt+1); else stageA_reg(nxt);
      if constexpr (PRE_B) stageB_gll(nxt, kt+1); else stageB_reg(nxt);
      if constexpr (!PRE_A) { if (kt+2 < NT) loadA(kt+2); }
      if constexpr (!PRE_B) { if (kt+2 < NT) loadB(kt+2); }
    }

    const ushort_t* as = As[cur];
    const ushort_t* bs = Bs[cur];
    #pragma unroll
    for (int kk=0; kk<2; ++kk){
      bf16x8 af[4], bf[4];
      const int klo = kk*32 + ((lane>>4)<<3);
      #pragma unroll
      for (int mf=0; mf<4; ++mf){
        int r = wr*64 + mf*16 + (lane&15);
        int idx = (r*BK + klo) ^ ((r&7)<<3);
        af[mf] = *(const bf16x8*)&as[idx];
      }
      #pragma unroll
      for (int nf=0; nf<4; ++nf){
        int r = wc*64 + nf*16 + (lane&15);
        int idx = (r*BK + klo) ^ ((r&7)<<3);
        bf[nf] = *(const bf16x8*)&bs[idx];
      }
      #pragma unroll
      for (int mf=0; mf<4; ++mf)
        #pragma unroll
        for (int nf=0; nf<4; ++nf)
          acc[mf][nf] = __builtin_amdgcn_mfma_f32_16x16x32_bf16(af[mf], bf[nf], acc[mf][nf], 0, 0, 0);
    }
    cur = nxt;
  }

  // epilogue: C/D layout col=lane&15, row=(lane>>4)*4+i  [m89-verified]
  const int cl = lane & 15;
  const int rq = (lane >> 4) << 2;
  #pragma unroll
  for (int nf=0; nf<4; ++nf){
    int col = bcol + wc*64 + nf*16 + cl;
    float bvs = g_bias[col];
    #pragma unroll
    for (int mf=0; mf<4; ++mf){
      int row = brow + wr*64 + mf*16 + rq;
      f32x4 v = acc[mf][nf];
      #pragma unroll
      for (int i=0;i<4;++i)
        Y[(size_t)(row+i)*N_DIM + col] = v[i] + bvs;
    }
  }
}

// ---------------- launch ----------------
extern "C" void kernel_launch(void* const* d_in, const int* in_sizes, int n_in,
                              void* d_out, int out_size, void* d_ws, size_t ws_size,
                              hipStream_t stream) {
  const float* x     = (const float*)d_in[0];
  const int*   qw    = (const int*)  d_in[1];
  const float* scale = (const float*)d_in[2];
  const float* zp    = (const float*)d_in[3];
  const float* bias  = (const float*)d_in[4];
  float* y = (float*)d_out;

  const size_t XB = (size_t)M_DIM*K_DIM*2;  // 67,108,864
  const size_t WB = (size_t)N_DIM*K_DIM*2;  // 90,177,536

  dim3 grid(NWG), blk(256);

  if (ws_size >= XB + WB){
    ushort_t* xb = (ushort_t*)d_ws;
    ushort_t* wb = (ushort_t*)((char*)d_ws + XB);
    cvt_x_kernel<<<2048, 256, 0, stream>>>(x, xb);
    cvt_w_kernel<<<2048, 256, 0, stream>>>(qw, scale, zp, wb);
    qgemm<true,true><<<grid, blk, 0, stream>>>(xb, nullptr, wb, nullptr, scale, zp, bias, y);
  } else if (ws_size >= WB){
    ushort_t* wb = (ushort_t*)d_ws;
    cvt_w_kernel<<<2048, 256, 0, stream>>>(qw, scale, zp, wb);
    qgemm<false,true><<<grid, blk, 0, stream>>>(nullptr, x, wb, nullptr, scale, zp, bias, y);
  } else {
    qgemm<false,false><<<grid, blk, 0, stream>>>(nullptr, x, nullptr, qw, scale, zp, bias, y);
  }
}

// Round 3
// 926.210 us; speedup vs baseline: 1.2394x; 1.2394x over previous
//
#include <hip/hip_runtime.h>
#include <hip/hip_bf16.h>
#include <stdint.h>

// ---------------- problem constants ----------------
#define M_DIM 8192            // B*S = 4*2048
#define N_DIM 11008
#define K_DIM 4096
#define NTILE 64              // K-tiles of 64: K/64

typedef unsigned short ushort_t;
typedef __attribute__((ext_vector_type(8))) short  short8;
typedef __attribute__((ext_vector_type(8))) __bf16 bf16x8;
typedef __attribute__((ext_vector_type(4))) float  f32x4;

__device__ __forceinline__ ushort_t f2bf(float f){
  uint32_t u = __builtin_bit_cast(uint32_t, f);
  u += 0x7FFFu + ((u >> 16) & 1u);
  return (ushort_t)(u >> 16);
}

__device__ __forceinline__ void gll16(const void* g, void* l){
  __builtin_amdgcn_global_load_lds(
      (const __attribute__((address_space(1))) void*)g,
      (__attribute__((address_space(3))) void*)l,
      16, 0, 0);
}

// ---------------- pre-pass converts ----------------
__global__ void cvt_x_kernel(const float* __restrict__ x, ushort_t* __restrict__ xb){
  const int TOT = 33554432/8;
  for (int c = blockIdx.x*blockDim.x + threadIdx.x; c < TOT; c += gridDim.x*blockDim.x){
    size_t i = (size_t)c*8;
    float4 v0 = *(const float4*)(x+i);
    float4 v1 = *(const float4*)(x+i+4);
    short8 o;
    o[0]=(short)f2bf(v0.x); o[1]=(short)f2bf(v0.y); o[2]=(short)f2bf(v0.z); o[3]=(short)f2bf(v0.w);
    o[4]=(short)f2bf(v1.x); o[5]=(short)f2bf(v1.y); o[6]=(short)f2bf(v1.z); o[7]=(short)f2bf(v1.w);
    *(short8*)(xb+i) = o;
  }
}

__global__ void cvt_w_kernel(const int* __restrict__ q, const float* __restrict__ scale,
                             const float* __restrict__ zp, ushort_t* __restrict__ wb){
  const int TOT = 45088768/8;
  for (int c = blockIdx.x*blockDim.x + threadIdx.x; c < TOT; c += gridDim.x*blockDim.x){
    int row = c >> 9;
    float s = scale[row];
    float b = -zp[row]*s;
    size_t i = (size_t)c*8;
    int4 q0 = *(const int4*)(q+i);
    int4 q1 = *(const int4*)(q+i+4);
    short8 o;
    o[0]=(short)f2bf((float)q0.x*s+b); o[1]=(short)f2bf((float)q0.y*s+b);
    o[2]=(short)f2bf((float)q0.z*s+b); o[3]=(short)f2bf((float)q0.w*s+b);
    o[4]=(short)f2bf((float)q1.x*s+b); o[5]=(short)f2bf((float)q1.y*s+b);
    o[6]=(short)f2bf((float)q1.z*s+b); o[7]=(short)f2bf((float)q1.w*s+b);
    *(short8*)(wb+i) = o;
  }
}

// ============== 256x256 8-phase GEMM (T2+T3+T4+T5), path A ==============
// C[M][N] = Xb[M][K] * Wb[N][K]^T + bias. 512 thr = 8 waves (2M x 4N),
// per-wave 128x64 out. LDS: A/B tiles 256x64 as 2 halves of [128][64],
// double-buffered = 128 KB. XOR swizzle (slot^row&7) on 16B granules, same
// scheme round 2 measured 0 bank conflicts with.
//
// Per iter j: compute tiles 2j (buf0), 2j+1 (buf1); stage one half-tile per
// phase; counted vmcnt(4) only at phases 4 and 8:
//  ph1: rd A0.g0,B0.n01  | stage A[b1].h1 <- 2j+1 | mfma Q(0,0) buf0
//  ph2: rd B0.n23        | stage B[b1].h1 <- 2j+1 | mfma Q(0,1)
//  ph3: rd A0.g1         | stage B[b0].h0 <- 2j+2 | mfma Q(1,0)
//  ph4:                  | stage A[b0].h0 <- 2j+2 | vmcnt(4) | mfma Q(1,1)
//  ph5: rd A1.g0,B1.n01  | stage A[b0].h1 <- 2j+2 | mfma Q(0,0) buf1
//  ph6: rd B1.n23        | stage B[b0].h1 <- 2j+2 | mfma Q(0,1)
//  ph7: rd A1.g1         | stage B[b1].h0 <- 2j+3 | mfma Q(1,0)
//  ph8:                  | stage A[b1].h0 <- 2j+3 | vmcnt(4) | mfma Q(1,1)
// WAR: each stage targets a half whose last read's consuming MFMA closed >=1
// barrier earlier. RAW: vmcnt(4)@ph4 lands all buf1 stages (ph7,8 prev + 1,2)
// before ph5 reads; vmcnt(4)@ph8 lands all buf0 stages (ph3..6) before next
// ph1 reads. Raw s_barrier (no implicit vmcnt drain).

#define BAR() do{ asm volatile("" ::: "memory"); \
  __builtin_amdgcn_sched_barrier(0); \
  __builtin_amdgcn_s_barrier(); \
  __builtin_amdgcn_sched_barrier(0); \
  asm volatile("" ::: "memory"); }while(0)

#define VMCNT4() asm volatile("s_waitcnt vmcnt(4)" ::: "memory")

#define LDA(BUF, G) do{ \
  const ushort_t* _b = &As[BUF][wm][((G)*64 + rl)*64]; \
  _Pragma("unroll") for (int mf=0; mf<4; ++mf){ \
    af[mf][0] = *(const bf16x8*)(_b + mf*1024 + offk0); \
    af[mf][1] = *(const bf16x8*)(_b + mf*1024 + offk1); } \
}while(0)

#define LDB(BUF, NG) do{ \
  const ushort_t* _b = &Bs[BUF][hb][(hbr + (NG)*32 + rl)*64]; \
  _Pragma("unroll") for (int nfl=0; nfl<2; ++nfl){ \
    bf[(NG)*2+nfl][0] = *(const bf16x8*)(_b + nfl*1024 + offk0); \
    bf[(NG)*2+nfl][1] = *(const bf16x8*)(_b + nfl*1024 + offk1); } \
}while(0)

#define MFMA_Q(MG, NG) do{ \
  __builtin_amdgcn_s_setprio(1); \
  _Pragma("unroll") for (int mf=0; mf<4; ++mf) \
    _Pragma("unroll") for (int nfl=0; nfl<2; ++nfl) \
      _Pragma("unroll") for (int kk=0; kk<2; ++kk) \
        acc[(MG)*4+mf][(NG)*2+nfl] = __builtin_amdgcn_mfma_f32_16x16x32_bf16( \
            af[mf][kk], bf[(NG)*2+nfl][kk], acc[(MG)*4+mf][(NG)*2+nfl], 0,0,0); \
  __builtin_amdgcn_s_setprio(0); \
}while(0)

#define STAGE_A(BUF, H, T) do{ if ((T) < NTILE){ \
  gll16(aS[H][0] + (size_t)(T)*64, &As[BUF][H][w*1024]); \
  gll16(aS[H][1] + (size_t)(T)*64, &As[BUF][H][w*1024+512]); } }while(0)

#define STAGE_B(BUF, H, T) do{ if ((T) < NTILE){ \
  gll16(bS[H][0] + (size_t)(T)*64, &Bs[BUF][H][w*1024]); \
  gll16(bS[H][1] + (size_t)(T)*64, &Bs[BUF][H][w*1024+512]); } }while(0)

__global__ __launch_bounds__(512, 2)
void qgemm256(const ushort_t* __restrict__ Xb, const ushort_t* __restrict__ Wb,
              const float* __restrict__ g_bias, float* __restrict__ Y)
{
  __shared__ __align__(16) ushort_t As[2][2][8192];   // 64 KB
  __shared__ __align__(16) ushort_t Bs[2][2][8192];   // 64 KB

  const int t    = threadIdx.x;
  const int lane = t & 63;
  const int w    = t >> 6;        // 0..7
  const int wm   = w >> 2;        // 0..1  (M half)
  const int wn   = w & 3;         // 0..3  (N quarter)
  const int hb   = wn >> 1;       // B half
  const int hbr  = (wn & 1) * 64; // row base within B half

  const int GM2 = M_DIM/256, GN2 = N_DIM/256;   // 32, 43
  const int NWG2 = GM2*GN2;                      // 1376 (%8==0)
  int bid = blockIdx.x;
  int swz = (bid & 7) * (NWG2/8) + (bid >> 3);
  int by = swz / GN2, bx = swz - by*GN2;
  const int brow = by*256, bcol = bx*256;

  // ds_read per-thread constants (swizzle folds to a constant XOR per thread)
  const int rl    = lane & 15;
  const int offk0 = (((lane>>4)    ) ^ (lane&7)) * 8;   // kk=0, elements
  const int offk1 = (((lane>>4) + 4) ^ (lane&7)) * 8;   // kk=1

  // staging geometry: wave w owns chunks 2w,2w+1 of each half-tile (8 rows,
  // 1 KB each); lane fetches pre-swizzled global slot so LDS lands swizzled.
  const int g_r = lane >> 3;
  const int g_s = (lane & 7) ^ g_r;
  const ushort_t* aS[2][2];
  const ushort_t* bS[2][2];
  #pragma unroll
  for (int h=0; h<2; ++h)
    #pragma unroll
    for (int ci=0; ci<2; ++ci){
      int r8 = 8*(2*w+ci) + g_r;
      aS[h][ci] = Xb + (size_t)(brow + h*128 + r8)*K_DIM + g_s*8;
      bS[h][ci] = Wb + (size_t)(bcol + h*128 + r8)*K_DIM + g_s*8;
    }

  f32x4 acc[8][4] = {};
  bf16x8 af[4][2], bf[4][2];

  // ---- prologue: buf0 <- tile0 (4 halves), buf1 <- tile1 (B.h0, A.h0) ----
  STAGE_B(0,0,0); STAGE_A(0,0,0); STAGE_A(0,1,0); STAGE_B(0,1,0);
  STAGE_B(1,0,1); STAGE_A(1,0,1);
  VMCNT4();                 // allow the 2 buf1 stages outstanding; buf0 landed
  BAR();

  #pragma unroll 1
  for (int j=0; j<NTILE/2; ++j){
    const int t1 = 2*j+1, t2 = 2*j+2, t3 = 2*j+3;
    // ph1
    LDA(0,0); LDB(0,0);
    STAGE_A(1,1,t1);
    BAR(); MFMA_Q(0,0); BAR();
    // ph2
    LDB(0,1);
    STAGE_B(1,1,t1);
    BAR(); MFMA_Q(0,1); BAR();
    // ph3
    LDA(0,1);
    STAGE_B(0,0,t2);
    BAR(); MFMA_Q(1,0); BAR();
    // ph4
    STAGE_A(0,0,t2);
    VMCNT4();
    BAR(); MFMA_Q(1,1); BAR();
    // ph5
    LDA(1,0); LDB(1,0);
    STAGE_A(0,1,t2);
    BAR(); MFMA_Q(0,0); BAR();
    // ph6
    LDB(1,1);
    STAGE_B(0,1,t2);
    BAR(); MFMA_Q(0,1); BAR();
    // ph7
    LDA(1,1);
    STAGE_B(1,0,t3);
    BAR(); MFMA_Q(1,0); BAR();
    // ph8
    STAGE_A(1,0,t3);
    VMCNT4();
    BAR(); MFMA_Q(1,1); BAR();
  }

  // ---- epilogue: C/D layout col=lane&15, row=(lane>>4)*4+i ----
  const int cl = lane & 15;
  const int rq = (lane >> 4) << 2;
  #pragma unroll
  for (int nf=0; nf<4; ++nf){
    int col = bcol + wn*64 + nf*16 + cl;
    float bvs = g_bias[col];
    #pragma unroll
    for (int mf=0; mf<8; ++mf){
      int row = brow + wm*128 + mf*16 + rq;
      f32x4 v = acc[mf][nf];
      #pragma unroll
      for (int i=0;i<4;++i)
        Y[(size_t)(row+i)*N_DIM + col] = v[i] + bvs;
    }
  }
}

// ============== fallback 128x128 dbuf GEMM (paths B/C, proven r2) ==============
template<bool PRE_A, bool PRE_B>
__global__ __launch_bounds__(256, 2)
void qgemm(const ushort_t* __restrict__ Xb, const float* __restrict__ Xf,
           const ushort_t* __restrict__ Wb, const int* __restrict__ Wq,
           const float* __restrict__ g_scale, const float* __restrict__ g_zp,
           const float* __restrict__ g_bias, float* __restrict__ Y)
{
  const int BM=128, BK=64, NT=K_DIM/BK, GRID_N=N_DIM/128, NWG=(M_DIM/128)*GRID_N;
  __shared__ __align__(16) ushort_t As[2][BM*BK];
  __shared__ __align__(16) ushort_t Bs[2][BM*BK];

  const int t = threadIdx.x, lane = t & 63, w = t >> 6;
  const int wr = w >> 1, wc = w & 1;
  int bid = blockIdx.x;
  int swz = (bid & 7) * (NWG/8) + (bid >> 3);
  int by = swz / GRID_N, bx = swz - by*GRID_N;
  const int brow = by*128, bcol = bx*128;

  f32x4 acc[4][4] = {};
  const int s8 = t & 7, r0 = t >> 3;
  const int g_r = lane >> 3, g_s = (lane & 7) ^ g_r;

  float wsc[4], wof[4];
  if constexpr (!PRE_B){
    #pragma unroll
    for (int i=0;i<4;++i){
      int n = bcol + r0 + 32*i;
      float sc = g_scale[n];
      wsc[i] = sc; wof[i] = -g_zp[n]*sc;
    }
  }
  float4 ax[4][2]; int4 bq[4][2];
  auto loadA = [&](int kt){
    #pragma unroll
    for (int i=0;i<4;++i){
      const float* p = Xf + (size_t)(brow + r0 + 32*i)*K_DIM + kt*BK + s8*8;
      ax[i][0] = *(const float4*)p; ax[i][1] = *(const float4*)(p+4);
    }};
  auto loadB = [&](int kt){
    #pragma unroll
    for (int i=0;i<4;++i){
      const int* p = Wq + (size_t)(bcol + r0 + 32*i)*K_DIM + kt*BK + s8*8;
      bq[i][0] = *(const int4*)p; bq[i][1] = *(const int4*)(p+4);
    }};
  auto stageA_gll = [&](int buf, int kt){
    #pragma unroll
    for (int i=0;i<4;++i){ int c = w*4 + i;
      gll16(Xb + (size_t)(brow + 8*c + g_r)*K_DIM + kt*BK + g_s*8, &As[buf][c*512]); }};
  auto stageB_gll = [&](int buf, int kt){
    #pragma unroll
    for (int i=0;i<4;++i){ int c = w*4 + i;
      gll16(Wb + (size_t)(bcol + 8*c + g_r)*K_DIM + kt*BK + g_s*8, &Bs[buf][c*512]); }};
  auto stageA_reg = [&](int buf){
    #pragma unroll
    for (int i=0;i<4;++i){
      short8 o;
      o[0]=(short)f2bf(ax[i][0].x); o[1]=(short)f2bf(ax[i][0].y);
      o[2]=(short)f2bf(ax[i][0].z); o[3]=(short)f2bf(ax[i][0].w);
      o[4]=(short)f2bf(ax[i][1].x); o[5]=(short)f2bf(ax[i][1].y);
      o[6]=(short)f2bf(ax[i][1].z); o[7]=(short)f2bf(ax[i][1].w);
      int r = r0 + 32*i; int idx = (r*BK + s8*8) ^ ((r&7)<<3);
      *(short8*)&As[buf][idx] = o; }};
  auto stageB_reg = [&](int buf){
    #pragma unroll
    for (int i=0;i<4;++i){
      short8 o;
      o[0]=(short)f2bf((float)bq[i][0].x*wsc[i]+wof[i]);
      o[1]=(short)f2bf((float)bq[i][0].y*wsc[i]+wof[i]);
      o[2]=(short)f2bf((float)bq[i][0].z*wsc[i]+wof[i]);
      o[3]=(short)f2bf((float)bq[i][0].w*wsc[i]+wof[i]);
      o[4]=(short)f2bf((float)bq[i][1].x*wsc[i]+wof[i]);
      o[5]=(short)f2bf((float)bq[i][1].y*wsc[i]+wof[i]);
      o[6]=(short)f2bf((float)bq[i][1].z*wsc[i]+wof[i]);
      o[7]=(short)f2bf((float)bq[i][1].w*wsc[i]+wof[i]);
      int r = r0 + 32*i; int idx = (r*BK + s8*8) ^ ((r&7)<<3);
      *(short8*)&Bs[buf][idx] = o; }};

  if constexpr (!PRE_A) loadA(0);
  if constexpr (!PRE_B) loadB(0);
  if constexpr (PRE_A) stageA_gll(0,0); else stageA_reg(0);
  if constexpr (PRE_B) stageB_gll(0,0); else stageB_reg(0);
  if constexpr (!PRE_A) { if (NT > 1) loadA(1); }
  if constexpr (!PRE_B) { if (NT > 1) loadB(1); }

  int cur = 0;
  for (int kt=0; kt<NT; ++kt){
    asm volatile("s_waitcnt vmcnt(0) lgkmcnt(0)" ::: "memory");
    __builtin_amdgcn_sched_barrier(0);
    __syncthreads();
    const int nxt = cur ^ 1;
    if (kt+1 < NT){
      if constexpr (PRE_A) stageA_gll(nxt, kt+1); else stageA_reg(nxt);
      if constexpr (PRE_B) stageB_gll(nxt, kt+1); else stageB_reg(nxt);
      if constexpr (!PRE_A) { if (kt+2 < NT) loadA(kt+2); }
      if constexpr (!PRE_B) { if (kt+2 < NT) loadB(kt+2); }
    }
    const ushort_t* as = As[cur];
    const ushort_t* bs = Bs[cur];
    #pragma unroll
    for (int kk=0; kk<2; ++kk){
      bf16x8 af[4], bfr[4];
      const int klo = kk*32 + ((lane>>4)<<3);
      #pragma unroll
      for (int mf=0; mf<4; ++mf){
        int r = wr*64 + mf*16 + (lane&15);
        af[mf] = *(const bf16x8*)&as[(r*BK + klo) ^ ((r&7)<<3)];
      }
      #pragma unroll
      for (int nf=0; nf<4; ++nf){
        int r = wc*64 + nf*16 + (lane&15);
        bfr[nf] = *(const bf16x8*)&bs[(r*BK + klo) ^ ((r&7)<<3)];
      }
      #pragma unroll
      for (int mf=0; mf<4; ++mf)
        #pragma unroll
        for (int nf=0; nf<4; ++nf)
          acc[mf][nf] = __builtin_amdgcn_mfma_f32_16x16x32_bf16(af[mf], bfr[nf], acc[mf][nf], 0,0,0);
    }
    cur = nxt;
  }
  const int cl = lane & 15, rq = (lane >> 4) << 2;
  #pragma unroll
  for (int nf=0; nf<4; ++nf){
    int col = bcol + wc*64 + nf*16 + cl;
    float bvs = g_bias[col];
    #pragma unroll
    for (int mf=0; mf<4; ++mf){
      int row = brow + wr*64 + mf*16 + rq;
      f32x4 v = acc[mf][nf];
      #pragma unroll
      for (int i=0;i<4;++i)
        Y[(size_t)(row+i)*N_DIM + col] = v[i] + bvs;
    }
  }
}

// ---------------- launch ----------------
extern "C" void kernel_launch(void* const* d_in, const int* in_sizes, int n_in,
                              void* d_out, int out_size, void* d_ws, size_t ws_size,
                              hipStream_t stream) {
  const float* x     = (const float*)d_in[0];
  const int*   qw    = (const int*)  d_in[1];
  const float* scale = (const float*)d_in[2];
  const float* zp    = (const float*)d_in[3];
  const float* bias  = (const float*)d_in[4];
  float* y = (float*)d_out;

  const size_t XB = (size_t)M_DIM*K_DIM*2;
  const size_t WB = (size_t)N_DIM*K_DIM*2;

  if (ws_size >= XB + WB){
    ushort_t* xb = (ushort_t*)d_ws;
    ushort_t* wb = (ushort_t*)((char*)d_ws + XB);
    cvt_x_kernel<<<2048, 256, 0, stream>>>(x, xb);
    cvt_w_kernel<<<2048, 256, 0, stream>>>(qw, scale, zp, wb);
    qgemm256<<<dim3((M_DIM/256)*(N_DIM/256)), dim3(512), 0, stream>>>(xb, wb, bias, y);
  } else if (ws_size >= WB){
    ushort_t* wb = (ushort_t*)d_ws;
    cvt_w_kernel<<<2048, 256, 0, stream>>>(qw, scale, zp, wb);
    qgemm<false,true><<<dim3((M_DIM/128)*(N_DIM/128)), dim3(256), 0, stream>>>(nullptr, x, wb, nullptr, scale, zp, bias, y);
  } else {
    qgemm<false,false><<<dim3((M_DIM/128)*(N_DIM/128)), dim3(256), 0, stream>>>(nullptr, x, nullptr, qw, scale, zp, bias, y);
  }
}